// Round 6
// baseline (167.516 us; speedup 1.0000x reference)
//
#include <hip/hip_runtime.h>
#include <hip/hip_bf16.h>
#include <math.h>

#define S_LEN 2048
#define HDIM  2048
#define N_H   16
#define N_KV  2
#define HD_   128
#define NQKV  2560

typedef __attribute__((ext_vector_type(8))) short bf16x8;
typedef __attribute__((ext_vector_type(4))) float f32x4;
typedef __attribute__((ext_vector_type(16))) float f32x16;

#define GLDS16(gsrc, ldst)                                                      \
  __builtin_amdgcn_global_load_lds(                                             \
      (const __attribute__((address_space(1))) void*)(gsrc),                    \
      (__attribute__((address_space(3))) void*)(ldst), 16, 0, 0)

__device__ __forceinline__ ushort f2b(float x) {
  union { __hip_bfloat16 b; ushort u; } c;
  c.b = __float2bfloat16(x);
  return c.u;
}
__device__ __forceinline__ float b2f(ushort u) {
  union { float f; unsigned v; } c;
  c.v = ((unsigned)u) << 16;
  return c.f;
}
__device__ __forceinline__ uint pk2(float a, float b) {
  return (uint)f2b(a) | ((uint)f2b(b) << 16);
}

// ---------------- f32 -> bf16 elementwise (x conversion) ----------------
__global__ __launch_bounds__(256) void k_f32_to_bf16(const float* __restrict__ src,
                                                     ushort* __restrict__ dst, int n4) {
  int i = blockIdx.x * 256 + threadIdx.x;
  if (i >= n4) return;
  float4 v = ((const float4*)src)[i];
  ushort4 o;
  o.x = f2b(v.x); o.y = f2b(v.y); o.z = f2b(v.z); o.w = f2b(v.w);
  ((ushort4*)dst)[i] = o;
}

// ---------------- f32 [R][C] -> bf16 [C][R] tiled transpose ----------------
__global__ __launch_bounds__(256) void k_transpose_bf16(const float* __restrict__ src,
                                                        ushort* __restrict__ dst,
                                                        int R, int C) {
  __shared__ float t[64][65];
  int c0 = blockIdx.x * 64, r0 = blockIdx.y * 64;
  int tx = threadIdx.x & 63, ty = threadIdx.x >> 6;
#pragma unroll
  for (int i = 0; i < 16; ++i)
    t[i * 4 + ty][tx] = src[(size_t)(r0 + i * 4 + ty) * C + (c0 + tx)];
  __syncthreads();
#pragma unroll
  for (int i = 0; i < 16; ++i)
    dst[(size_t)(c0 + i * 4 + ty) * R + (r0 + tx)] = f2b(t[tx][i * 4 + ty]);
}

// ------- bf16 GEMM 128x128, K-split via blockIdx.z; bf16 partial slices -----
__global__ __launch_bounds__(256) void k_gemm_bt(const ushort* __restrict__ A,
                                                 const ushort* __restrict__ Bt,
                                                 ushort* __restrict__ Cp,
                                                 int M, int N, int Kfull, int Khalf) {
  __shared__ ushort lA[128 * 32];
  __shared__ ushort lB[128 * 32];
  const int tid = threadIdx.x;
  const int w = tid >> 6, lane = tid & 63;
  const int lr = lane & 15, lg = lane >> 4;
  const int bm = blockIdx.x * 128, bn = blockIdx.y * 128;
  const int wm = (w >> 1) * 64, wn = (w & 1) * 64;
  const int kbeg = blockIdx.z * Khalf;
  ushort* Cout = Cp + (size_t)blockIdx.z * M * N;
  f32x4 acc[4][4] = {};

  for (int k0 = kbeg; k0 < kbeg + Khalf; k0 += 32) {
    __syncthreads();
#pragma unroll
    for (int it = 0; it < 2; ++it) {
      const int idx = it * 256 + tid;
      const int row = idx >> 2;
      const int kc = (idx & 3) * 8;
      GLDS16(A + (size_t)(bm + row) * Kfull + k0 + kc, lA + (it * 4 + w) * 512);
      GLDS16(Bt + (size_t)(bn + row) * Kfull + k0 + kc, lB + (it * 4 + w) * 512);
    }
    __syncthreads();
    bf16x8 af[4], bf[4];
#pragma unroll
    for (int i = 0; i < 4; ++i) {
      af[i] = *(const bf16x8*)(lA + (wm + i * 16 + lr) * 32 + lg * 8);
      bf[i] = *(const bf16x8*)(lB + (wn + i * 16 + lr) * 32 + lg * 8);
    }
    __builtin_amdgcn_s_setprio(1);
#pragma unroll
    for (int mi = 0; mi < 4; ++mi)
#pragma unroll
      for (int ni = 0; ni < 4; ++ni)
        acc[mi][ni] =
            __builtin_amdgcn_mfma_f32_16x16x32_bf16(af[mi], bf[ni], acc[mi][ni], 0, 0, 0);
    __builtin_amdgcn_s_setprio(0);
  }

#pragma unroll
  for (int mi = 0; mi < 4; ++mi)
#pragma unroll
    for (int ni = 0; ni < 4; ++ni)
#pragma unroll
      for (int r = 0; r < 4; ++r) {
        const int row = bm + wm + mi * 16 + lg * 4 + r;
        const int col = bn + wn + ni * 16 + lr;
        Cout[(size_t)row * N + col] = f2b(acc[mi][ni][r]);
      }
}

// ------- fused QKV epilogue (partials+bias, bf16 semantics) + RoPE ---------
__global__ __launch_bounds__(256) void k_epirope(const ushort* __restrict__ p0,
                                                 const ushort* __restrict__ p1,
                                                 const float* __restrict__ bq,
                                                 const float* __restrict__ bk,
                                                 const float* __restrict__ bv,
                                                 const int* __restrict__ pos_ids,
                                                 ushort* __restrict__ q_r,
                                                 ushort* __restrict__ k_r,
                                                 ushort* __restrict__ v_t,
                                                 float* __restrict__ cache_k,
                                                 float* __restrict__ cache_v) {
  const int s = blockIdx.x;
  const int t = threadIdx.x;
  __shared__ float row[NQKV];
  const uint* a = (const uint*)(p0 + (size_t)s * NQKV);
  const uint* b = (const uint*)(p1 + (size_t)s * NQKV);
#pragma unroll
  for (int j = 0; j < 5; ++j) {
    const int c2 = t + 256 * j;  // 1280 uint pairs
    const uint u0 = a[c2], u1 = b[c2];
    const int c = 2 * c2;
    const float v0 = b2f((ushort)u0) + b2f((ushort)(u1 & 0xffff));
    const float v1 = b2f((ushort)(u0 >> 16)) + b2f((ushort)(u1 >> 16));
    const float bias0 = (c < 2048) ? bq[c] : (c < 2304 ? bk[c - 2048] : bv[c - 2304]);
    const float bias1 = (c + 1 < 2048) ? bq[c + 1]
                                       : (c + 1 < 2304 ? bk[c + 1 - 2048] : bv[c + 1 - 2304]);
    row[c] = b2f(f2b(b2f(f2b(v0)) + b2f(f2b(bias0))));
    row[c + 1] = b2f(f2b(b2f(f2b(v1)) + b2f(f2b(bias1))));
  }
  __syncthreads();

  const int i = t & 63, g = t >> 6;
  const float SCALE = 0.08838834764831845f;  // 1/sqrt(128)
  const float pos = (float)pos_ids[s];
  const float freq = (float)(1.0 / pow(1000000.0, (double)i / 64.0));
  float sn, cs;
  sincosf(pos * freq, &sn, &cs);

#pragma unroll
  for (int j = 0; j < 4; ++j) {
    const int h = j * 4 + g;
    const float x1 = row[h * 128 + i];
    const float x2 = row[h * 128 + 64 + i];
    const float o1 = x1 * cs - x2 * sn;
    const float o2 = x1 * sn + x2 * cs;
    const size_t qo = ((size_t)h * S_LEN + s) * 128;
    q_r[qo + i] = f2b(o1 * SCALE);
    q_r[qo + 64 + i] = f2b(o2 * SCALE);
  }
  if (g < 2) {
    const int kv = g;
    const float x1 = row[2048 + kv * 128 + i];
    const float x2 = row[2048 + kv * 128 + 64 + i];
    const float o1 = x1 * cs - x2 * sn;
    const float o2 = x1 * sn + x2 * cs;
    const size_t ko = ((size_t)kv * S_LEN + s) * 128;
    k_r[ko + i] = f2b(o1);
    k_r[ko + 64 + i] = f2b(o2);
    const size_t co = ((size_t)s * 2 + kv) * 128;
    cache_k[co + i] = o1;
    cache_k[co + 64 + i] = o2;
  }
  {
    const int kv = t >> 7, d = t & 127;
    const float vval = row[2304 + kv * 128 + d];
    cache_v[((size_t)s * 2 + kv) * 128 + d] = vval;
    v_t[((size_t)kv * 128 + d) * S_LEN + s] = f2b(vval);
  }
}

// ------- out-proj epilogue: add 2 bf16 partial slices, round, f32 out ------
__global__ __launch_bounds__(256) void k_addround(const ushort* __restrict__ p0,
                                                  const ushort* __restrict__ p1,
                                                  float* __restrict__ out, int n2) {
  int i = blockIdx.x * 256 + threadIdx.x;
  if (i >= n2) return;
  const uint a = ((const uint*)p0)[i];
  const uint b = ((const uint*)p1)[i];
  float2 o;
  o.x = b2f(f2b(b2f((ushort)(a & 0xffff)) + b2f((ushort)(b & 0xffff))));
  o.y = b2f(f2b(b2f((ushort)(a >> 16)) + b2f((ushort)(b >> 16))));
  ((float2*)out)[i] = o;
}

// ------------- flash attention phase A: split-KV chunks -------------------
// Grid 1280 = 16 heads x 80 chunks. Chunk j: band b (tiles Q=8b..8b+7 have
// b+1 chunks of <=8 64-key steps). qt64, KV-split-2 groups, 32-key tiles,
// double-buffered. Q<=7 (b==0): finalize inline. Else write bf16 partial
// O[64][128] + f32 (m,l) to slot h*72+(j-8); k_attn_merge combines.
__global__ __launch_bounds__(256, 2) void k_attn(const ushort* __restrict__ q_r,
                                                 const ushort* __restrict__ k_r,
                                                 const ushort* __restrict__ v_t,
                                                 ushort* __restrict__ attn_b,
                                                 ushort* __restrict__ pO,
                                                 float* __restrict__ pML) {
  __shared__ ushort smem[2][2][8192];  // [group][buf][K:0..4095 | V:4096..8191]
  __shared__ float stats[2][32][2];

  const int bi = blockIdx.x;
  const int h = bi & 15;
  const int j = bi >> 4;  // 0..79
  const int b = (j < 8) ? 0 : (j < 24) ? 1 : (j < 48) ? 2 : 3;
  const int rr = j - 4 * b * (b + 1);
  const int Q = 8 * b + rr / (b + 1);
  const int cch = rr % (b + 1);
  const int s_beg = 8 * cch;
  const int s_end = min(8 * cch + 8, Q + 1);
  const bool single = (b == 0);
  const int kvh = h >> 3;

  const int tid = threadIdx.x, w = tid >> 6, lane = tid & 63;
  const int g = w >> 1, wq = w & 1, tg = tid & 127;
  const int l31 = lane & 31, hb = lane >> 5;
  const int qmaxw = Q * 64 + wq * 32 + 31;

  // Q fragments (B-operand): lane holds Q[q=l31][hd = f*16 + 8*hb + j]
  bf16x8 qf[8];
  {
    const ushort* qp =
        q_r + ((size_t)(h * S_LEN + Q * 64 + wq * 32 + l31)) * 128 + hb * 8;
#pragma unroll
    for (int f = 0; f < 8; ++f) qf[f] = *(const bf16x8*)(qp + f * 16);
  }

  f32x16 acc[4] = {};  // O^T: [d-group] row=d, col=q
  float m = -INFINITY, l = 0.f;

#define STAGE(BUF, T32)                                                           \
  do {                                                                            \
    const int kb_ = (T32) * 32;                                                   \
    _Pragma("unroll") for (int i = 0; i < 4; ++i) {                               \
      const int idx = i * 128 + tg;                                               \
      {                                                                           \
        const int key = idx >> 4, sl = idx & 15;                                  \
        GLDS16(k_r + ((size_t)(kvh * S_LEN + kb_ + key)) * 128 +                  \
                   ((sl ^ (key & 7)) * 8),                                        \
               &smem[g][BUF][i * 1024 + wq * 512]);                               \
      }                                                                           \
      {                                                                           \
        const int d = idx >> 2, p = idx & 3;                                      \
        const int gs = (p - (d >> 1)) & 3;                                        \
        GLDS16(v_t + ((size_t)(kvh * HD_ + d)) * S_LEN + kb_ + gs * 8,            \
               &smem[g][BUF][4096 + i * 1024 + wq * 512]);                        \
      }                                                                           \
    }                                                                             \
  } while (0)

  STAGE(0, 2 * s_beg + g);
  int buf = 0;

  for (int s = s_beg; s < s_end; ++s) {
    __syncthreads();  // tile s ready (barrier drains vmcnt)
    if (s + 1 < s_end) STAGE(buf ^ 1, 2 * (s + 1) + g);
    const int kb = (2 * s + g) * 32;

    if (kb <= qmaxw) {
      const ushort* lK = &smem[g][buf][0];
      const ushort* lV = &smem[g][buf][4096];

      // QK^T: two independent 4-chains to halve dependent-MFMA latency
      f32x16 pa = {}, pb = {};
      __builtin_amdgcn_s_setprio(1);
#pragma unroll
      for (int f = 0; f < 4; ++f) {
        const int key = l31;
        const bf16x8 kf8 =
            *(const bf16x8*)(lK + key * 128 + (((2 * f + hb) ^ (key & 7)) * 8));
        pa = __builtin_amdgcn_mfma_f32_32x32x16_bf16(kf8, qf[f], pa, 0, 0, 0);
      }
#pragma unroll
      for (int f = 4; f < 8; ++f) {
        const int key = l31;
        const bf16x8 kf8 =
            *(const bf16x8*)(lK + key * 128 + (((2 * f + hb) ^ (key & 7)) * 8));
        pb = __builtin_amdgcn_mfma_f32_32x32x16_bf16(kf8, qf[f], pb, 0, 0, 0);
      }
      __builtin_amdgcn_s_setprio(0);
      const f32x16 p0 = pa + pb;

      // causal mask + tree max (16 vals/lane)
      const int q = Q * 64 + wq * 32 + l31;
      float sv[16];
#pragma unroll
      for (int r = 0; r < 16; ++r) {
        const int key = kb + (r & 3) + 8 * (r >> 2) + 4 * hb;
        sv[r] = (key <= q) ? p0[r] : -INFINITY;
      }
      float t8[8];
#pragma unroll
      for (int jj = 0; jj < 8; ++jj) t8[jj] = fmaxf(sv[jj], sv[jj + 8]);
#pragma unroll
      for (int st = 4; st >= 1; st >>= 1)
#pragma unroll
        for (int jj = 0; jj < 4; ++jj)
          if (jj < st) t8[jj] = fmaxf(t8[jj], t8[jj + st]);
      const float mxw = fmaxf(t8[0], __shfl_xor(t8[0], 32));

      // defer-max (T13)
      if (__any(mxw > m + 8.f)) {
        const float mn = fmaxf(m, mxw);
        const float sc = __expf(m - mn);
#pragma unroll
        for (int g2 = 0; g2 < 4; ++g2)
#pragma unroll
          for (int r = 0; r < 16; ++r) acc[g2][r] *= sc;
        l *= sc;
        m = mn;
      }
#pragma unroll
      for (int r = 0; r < 16; ++r) sv[r] = __expf(sv[r] - m);
      float ts[8];
#pragma unroll
      for (int jj = 0; jj < 8; ++jj) ts[jj] = sv[jj] + sv[jj + 8];
#pragma unroll
      for (int st = 4; st >= 1; st >>= 1)
#pragma unroll
        for (int jj = 0; jj < 4; ++jj)
          if (jj < st) ts[jj] += ts[jj + st];
      l += ts[0];

      // P -> bf16 fragments (cross-half exchange)
      uint pk8[8];
#pragma unroll
      for (int jj = 0; jj < 8; ++jj) pk8[jj] = pk2(sv[2 * jj], sv[2 * jj + 1]);
      union FragU { uint wd[4]; bf16x8 v; };
      FragU frag[2];
#pragma unroll
      for (int c1 = 0; c1 < 2; ++c1) {
        uint mine0, mine1, rcv0, rcv1;
        {
          const uint pa_ = pk8[0 + 4 * c1];
          const uint pb_ = pk8[2 + 4 * c1];
          const uint mn_ = hb ? pb_ : pa_;
          const uint xc_ = hb ? pa_ : pb_;
          mine0 = mn_;
          rcv0 = (uint)__shfl_xor((int)xc_, 32);
        }
        {
          const uint pa_ = pk8[1 + 4 * c1];
          const uint pb_ = pk8[3 + 4 * c1];
          const uint mn_ = hb ? pb_ : pa_;
          const uint xc_ = hb ? pa_ : pb_;
          mine1 = mn_;
          rcv1 = (uint)__shfl_xor((int)xc_, 32);
        }
        frag[c1].wd[0] = hb ? rcv0 : mine0;
        frag[c1].wd[1] = hb ? rcv1 : mine1;
        frag[c1].wd[2] = hb ? mine0 : rcv0;
        frag[c1].wd[3] = hb ? mine1 : rcv1;
      }

      // PV: acc[g2] += V^T[d-group g2] x P
      __builtin_amdgcn_s_setprio(1);
#pragma unroll
      for (int g2 = 0; g2 < 4; ++g2) {
        const int d = g2 * 32 + l31;
#pragma unroll
        for (int c = 0; c < 2; ++c) {
          const int phys = ((2 * c + hb) + (d >> 1)) & 3;
          const bf16x8 vf = *(const bf16x8*)(lV + d * 32 + phys * 8);
          acc[g2] = __builtin_amdgcn_mfma_f32_32x32x16_bf16(vf, frag[c].v, acc[g2], 0, 0, 0);
        }
      }
      __builtin_amdgcn_s_setprio(0);
    }
    buf ^= 1;
  }
  __syncthreads();  // all compute done before smem reuse for merge

  // -------- merge group1 state into group0, then finalize or spill --------
  float* mrg = (float*)&smem[0][0][0];   // [wq][128 d][32 q] = 32KB
  float* ldsO = (float*)&smem[1][0][0];  // [wq][32 q][128 d] = 32KB
  if (g == 1) {
    const float lt1 = l + __shfl_xor(l, 32);
#pragma unroll
    for (int g2 = 0; g2 < 4; ++g2)
#pragma unroll
      for (int r = 0; r < 16; ++r) {
        const int d5 = (r & 3) + 8 * (r >> 2) + 4 * hb;
        mrg[wq * 4096 + (g2 * 32 + d5) * 32 + l31] = acc[g2][r];
      }
    if (hb == 0) {
      stats[wq][l31][0] = m;
      stats[wq][l31][1] = lt1;
    }
  }
  __syncthreads();
  if (g == 0) {
    const int slot = h * 72 + (j - 8);  // valid only when !single
    const float m1 = stats[wq][l31][0];
    const float l1 = stats[wq][l31][1];
    const float l0 = l + __shfl_xor(l, 32);
    const float ms = fmaxf(m, m1);
    const float f0 = __expf(m - ms);
    const float f1 = __expf(m1 - ms);
    const float Lc = l0 * f0 + l1 * f1;
    const float inv = single ? 1.0f / Lc : 1.0f;
#pragma unroll
    for (int g2 = 0; g2 < 4; ++g2)
#pragma unroll
      for (int r = 0; r < 16; ++r) {
        const int d5 = (r & 3) + 8 * (r >> 2) + 4 * hb;
        const float o1v = mrg[wq * 4096 + (g2 * 32 + d5) * 32 + l31];
        const float val = (acc[g2][r] * f0 + o1v * f1) * inv;
        ldsO[wq * 4096 + l31 * 128 + g2 * 32 + (d5 ^ l31)] = val;
      }
    if (!single && hb == 0) {
      pML[(size_t)slot * 128 + (wq * 32 + l31) * 2] = ms;
      pML[(size_t)slot * 128 + (wq * 32 + l31) * 2 + 1] = Lc;
    }
#pragma unroll
    for (int pass = 0; pass < 8; ++pass) {
      const int qrow = pass * 4 + (lane >> 4);
      const int d0 = (lane & 15) * 8;
      float v[8];
#pragma unroll
      for (int jj = 0; jj < 8; ++jj)
        v[jj] = ldsO[wq * 4096 + qrow * 128 + (((d0 + jj) & 31) ^ qrow) + (d0 & 96)];
      uint4 o;
      o.x = pk2(v[0], v[1]); o.y = pk2(v[2], v[3]);
      o.z = pk2(v[4], v[5]); o.w = pk2(v[6], v[7]);
      if (single) {
        const size_t qg = (size_t)(Q * 64 + wq * 32 + qrow);
        *(uint4*)(attn_b + qg * HDIM + h * 128 + d0) = o;
      } else {
        *(uint4*)(pO + (size_t)slot * 8192 + (wq * 32 + qrow) * 128 + d0) = o;
      }
    }
  }
#undef STAGE
}

// ------------- flash attention phase B: merge partials --------------------
// Grid 384 = 16 h x 24 tiles (Q=8..31). P = Q/8+1 partials each.
__global__ __launch_bounds__(256) void k_attn_merge(const ushort* __restrict__ pO,
                                                    const float* __restrict__ pML,
                                                    ushort* __restrict__ attn_b) {
  const int bi = blockIdx.x;
  const int h = bi / 24, Q = 8 + bi % 24;
  const int b = Q >> 3;  // 1..3
  const int off = (b == 1) ? (Q - 8) * 2 : (b == 2) ? 16 + (Q - 16) * 3 : 40 + (Q - 24) * 4;
  const int P = b + 1;
  const int base = h * 72 + off;
  const int q = threadIdx.x >> 2, seg = (threadIdx.x & 3) * 32;

  const float* mlb = pML + (size_t)base * 128 + q * 2;
  const float m0 = mlb[0], l0 = mlb[1];
  const float m1 = mlb[128], l1 = mlb[129];
  const float m2 = (P > 2) ? mlb[256] : -INFINITY;
  const float l2 = (P > 2) ? mlb[257] : 0.f;
  const float m3 = (P > 3) ? mlb[384] : -INFINITY;
  const float l3 = (P > 3) ? mlb[385] : 0.f;
  const float ms = fmaxf(fmaxf(m0, m1), fmaxf(m2, m3));
  const float w0 = __expf(m0 - ms), w1 = __expf(m1 - ms);
  const float w2 = (P > 2) ? __expf(m2 - ms) : 0.f;
  const float w3 = (P > 3) ? __expf(m3 - ms) : 0.f;
  const float inv = 1.0f / (l0 * w0 + l1 * w1 + l2 * w2 + l3 * w3);

  const ushort* po = pO + (size_t)base * 8192 + q * 128;
  ushort* dst = attn_b + (size_t)(Q * 64 + q) * HDIM + h * 128;

#define ACC8(PTR, W)                                                    \
  {                                                                     \
    const uint4 v = *(const uint4*)(PTR);                               \
    o0 += b2f((ushort)(v.x & 0xffff)) * (W); o1 += b2f((ushort)(v.x >> 16)) * (W); \
    o2 += b2f((ushort)(v.y & 0xffff)) * (W); o3 += b2f((ushort)(v.y >> 16)) * (W); \
    o4 += b2f((ushort)(v.z & 0xffff)) * (W); o5 += b2f((ushort)(v.z >> 16)) * (W); \
    o6 += b2f((ushort)(v.w & 0xffff)) * (W); o7 += b2f((ushort)(v.w >> 16)) * (W); \
  }
#pragma unroll
  for (int u = 0; u < 4; ++u) {
    const int d = seg + u * 8;
    float o0 = 0, o1 = 0, o2 = 0, o3 = 0, o4 = 0, o5 = 0, o6 = 0, o7 = 0;
    ACC8(po + d, w0);
    ACC8(po + 8192 + d, w1);
    if (P > 2) ACC8(po + 2 * 8192 + d, w2);
    if (P > 3) ACC8(po + 3 * 8192 + d, w3);
    uint4 ov;
    ov.x = pk2(o0 * inv, o1 * inv); ov.y = pk2(o2 * inv, o3 * inv);
    ov.z = pk2(o4 * inv, o5 * inv); ov.w = pk2(o6 * inv, o7 * inv);
    *(uint4*)(dst + d) = ov;
  }
#undef ACC8
}

// ---------------- launch ----------------
extern "C" void kernel_launch(void* const* d_in, const int* in_sizes, int n_in,
                              void* d_out, int out_size, void* d_ws, size_t ws_size,
                              hipStream_t stream) {
  const float* hidden = (const float*)d_in[0];
  const int* pos_ids = (const int*)d_in[2];
  const float* Wq = (const float*)d_in[3];
  const float* bq = (const float*)d_in[4];
  const float* Wk = (const float*)d_in[5];
  const float* bk = (const float*)d_in[6];
  const float* Wv = (const float*)d_in[7];
  const float* bv = (const float*)d_in[8];
  const float* Wo = (const float*)d_in[9];

  float* out = (float*)d_out;
  float* cache_k = out + (size_t)S_LEN * HDIM;
  float* cache_v = cache_k + (size_t)S_LEN * N_KV * HD_;

  char* ws = (char*)d_ws;
  // Phase 1: x_b @0 (8M), wt @8M (10M), qkv partials @18M..38M (10M each)
  // Phase 2: wo_t @0, q_r @8M, k_r @16M, v_t @17M
  // Phase 3: attn_b @18M (8M); pO @26M (18M); pML @45M (0.6M)
  // Phase 4: outp @26M..42M (over pO, after merge), out add
  ushort* x_b = (ushort*)(ws);
  ushort* wt = (ushort*)(ws + (8ull << 20));
  ushort* qkvp = (ushort*)(ws + (18ull << 20));
  ushort* wo_t = (ushort*)(ws);
  ushort* q_r = (ushort*)(ws + (8ull << 20));
  ushort* k_r = (ushort*)(ws + (16ull << 20));
  ushort* v_t = (ushort*)(ws + (17ull << 20));
  ushort* attn_b = (ushort*)(ws + (18ull << 20));
  ushort* pO = (ushort*)(ws + (26ull << 20));
  float* pML = (float*)(ws + (45ull << 20));
  ushort* outp = (ushort*)(ws + (26ull << 20));

  k_f32_to_bf16<<<dim3((S_LEN * HDIM) / 1024), 256, 0, stream>>>(hidden, x_b,
                                                                 (S_LEN * HDIM) / 4);
  k_transpose_bf16<<<dim3(32, 32), 256, 0, stream>>>(Wq, wt, 2048, 2048);
  k_transpose_bf16<<<dim3(4, 32), 256, 0, stream>>>(Wk, wt + (size_t)2048 * 2048, 2048, 256);
  k_transpose_bf16<<<dim3(4, 32), 256, 0, stream>>>(Wv, wt + (size_t)2304 * 2048, 2048, 256);
  k_gemm_bt<<<dim3(16, 20, 2), 256, 0, stream>>>(x_b, wt, qkvp, 2048, 2560, 2048, 1024);
  k_transpose_bf16<<<dim3(32, 32), 256, 0, stream>>>(Wo, wo_t, 2048, 2048);  // x_b dead
  k_epirope<<<dim3(S_LEN), 256, 0, stream>>>(qkvp, qkvp + (size_t)2048 * 2560, bq, bk, bv,
                                             pos_ids, q_r, k_r, v_t, cache_k, cache_v);
  k_attn<<<dim3(1280), 256, 0, stream>>>(q_r, k_r, v_t, attn_b, pO, pML);
  k_attn_merge<<<dim3(384), 256, 0, stream>>>(pO, pML, attn_b);
  k_gemm_bt<<<dim3(16, 16, 2), 256, 0, stream>>>(attn_b, wo_t, outp, 2048, 2048, 2048, 1024);
  k_addround<<<dim3((2048 * 2048 / 2 + 255) / 256), 256, 0, stream>>>(
      outp, outp + (size_t)2048 * 2048, out, 2048 * 2048 / 2);
}